// Round 1
// baseline (1931.740 us; speedup 1.0000x reference)
//
#include <hip/hip_runtime.h>
#include <math.h>

#define N_NODES 50000
#define N_EDGES 800000
#define D 128
#define N_LAYERS 3

// ---------------------------------------------------------------------------
// Linear + bias + leaky_relu(0.2):  hout[r][c] = lrelu(sum_k hin[r][k]*W[k][c] + b[c])
// 32 rows per block, 256 threads: col = tid&127, row-within-pair = tid>>7.
// W staged in LDS in two 64-row K-chunks (32KB each) to stay under LDS limits.
// In-place safe (hin==hout): each row is read only by the block that writes it,
// and all reads happen before the epilogue stores.
// ---------------------------------------------------------------------------
__global__ __launch_bounds__(256) void linear_kernel(
    const float* __restrict__ hin, const float* __restrict__ W,
    const float* __restrict__ b, float* __restrict__ hout)
{
    __shared__ float Wl[64 * D];      // 32 KB: W rows [k_local][col]
    __shared__ float rowsl[32 * 64];  // 8 KB: h rows chunk [r_local][k_local]

    int tid = threadIdx.x;
    int base = blockIdx.x * 32;
    int col = tid & 127;
    int rsel = tid >> 7;

    float acc[16];
#pragma unroll
    for (int i = 0; i < 16; ++i) acc[i] = 0.f;

    for (int kc = 0; kc < 2; ++kc) {
        __syncthreads();  // protect LDS reuse from previous chunk
        // load W chunk (8192 floats)
        for (int j = tid * 4; j < 64 * D; j += 1024) {
            *(float4*)(Wl + j) = *(const float4*)(W + kc * 64 * D + j);
        }
        // load 32 rows x 64 k chunk
        for (int j = tid; j < 32 * 64; j += 256) {
            int r = j >> 6, k = j & 63;
            int gr = base + r;
            rowsl[j] = (gr < N_NODES) ? hin[(size_t)gr * D + kc * 64 + k] : 0.f;
        }
        __syncthreads();
#pragma unroll
        for (int i = 0; i < 16; ++i) {
            const float* hr = rowsl + (2 * i + rsel) * 64;
            float a = acc[i];
#pragma unroll
            for (int k = 0; k < 64; ++k)
                a = fmaf(hr[k], Wl[k * D + col], a);
            acc[i] = a;
        }
    }

    float bc = b[col];
#pragma unroll
    for (int i = 0; i < 16; ++i) {
        int r = base + 2 * i + rsel;
        if (r < N_NODES) {
            float v = acc[i] + bc;
            v = v > 0.f ? v : 0.2f * v;
            hout[(size_t)r * D + col] = v;
        }
    }
}

// ---------------------------------------------------------------------------
// Per-node attention dots: sl[n] = h[n]·aw[0:128], sr[n] = h[n]·aw[128:256]
// One wave per node; shuffle reduce over 64 lanes (2 elems/lane).
// ---------------------------------------------------------------------------
__global__ __launch_bounds__(256) void attn_dot_kernel(
    const float* __restrict__ h, const float* __restrict__ aw,
    float* __restrict__ sl, float* __restrict__ sr)
{
    int n = (blockIdx.x * 256 + threadIdx.x) >> 6;
    int lane = threadIdx.x & 63;
    if (n >= N_NODES) return;
    const float* hr = h + (size_t)n * D;
    float v0 = hr[lane], v1 = hr[lane + 64];
    float pl = v0 * aw[lane] + v1 * aw[lane + 64];
    float pr = v0 * aw[D + lane] + v1 * aw[D + lane + 64];
    for (int off = 32; off > 0; off >>= 1) {
        pl += __shfl_down(pl, off, 64);
        pr += __shfl_down(pr, off, 64);
    }
    if (lane == 0) { sl[n] = pl; sr[n] = pr; }
}

// Monotone float -> uint keymap for atomic max over floats (handles negatives).
__device__ __forceinline__ unsigned int float_to_key(float f) {
    unsigned int u = __float_as_uint(f);
    return (u & 0x80000000u) ? ~u : (u | 0x80000000u);
}
__device__ __forceinline__ float key_to_float(unsigned int u) {
    unsigned int fb = (u & 0x80000000u) ? (u & 0x7FFFFFFFu) : ~u;
    return __uint_as_float(fb);
}

// e = sl[src] + sr[dst] + b; store e; atomicMax key into m_u[src]
__global__ __launch_bounds__(256) void edge_max_kernel(
    const int* __restrict__ src, const int* __restrict__ dst,
    const float* __restrict__ sl, const float* __restrict__ sr,
    const float* __restrict__ attn_b,
    float* __restrict__ e_buf, unsigned int* __restrict__ m_u)
{
    int j = blockIdx.x * 256 + threadIdx.x;
    if (j >= N_EDGES) return;
    int s = src[j], d0 = dst[j];
    float e = sl[s] + sr[d0] + attn_b[0];
    e_buf[j] = e;
    atomicMax(m_u + s, float_to_key(e));
}

// ex = exp(e - m[src]); store in place; atomicAdd denom[src]
__global__ __launch_bounds__(256) void edge_exp_kernel(
    const int* __restrict__ src, float* __restrict__ e_buf,
    const unsigned int* __restrict__ m_u, float* __restrict__ denom)
{
    int j = blockIdx.x * 256 + threadIdx.x;
    if (j >= N_EDGES) return;
    int s = src[j];
    float m = key_to_float(m_u[s]);
    float ex = __expf(e_buf[j] - m);
    e_buf[j] = ex;
    atomicAdd(denom + s, ex);
}

// One wave per edge: h2[src] += h[dst] * (ex/denom[src]); 2 elems/lane.
__global__ __launch_bounds__(256) void edge_scatter_kernel(
    const int* __restrict__ src, const int* __restrict__ dst,
    const float* __restrict__ ex_buf, const float* __restrict__ denom,
    const float* __restrict__ h, float* __restrict__ h2)
{
    long long gid = (long long)blockIdx.x * 256 + threadIdx.x;
    int j = (int)(gid >> 6);
    int lane = threadIdx.x & 63;
    if (j >= N_EDGES) return;
    int s = src[j], d0 = dst[j];
    float w = ex_buf[j] / denom[s];
    const float* hr = h + (size_t)d0 * D;
    float* o = h2 + (size_t)s * D;
    float v0 = hr[lane], v1 = hr[lane + 64];
    atomicAdd(o + lane, v0 * w);
    atomicAdd(o + lane + 64, v1 * w);
}

// out = relu(h2); h2 = 0 (pre-zeroed for the next layer's scatter)
__global__ __launch_bounds__(256) void relu_zero_kernel(
    float4* __restrict__ h2, float4* __restrict__ out)
{
    int i = blockIdx.x * 256 + threadIdx.x;
    if (i >= N_NODES * D / 4) return;
    float4 v = h2[i];
    v.x = fmaxf(v.x, 0.f);
    v.y = fmaxf(v.y, 0.f);
    v.z = fmaxf(v.z, 0.f);
    v.w = fmaxf(v.w, 0.f);
    out[i] = v;
    h2[i] = make_float4(0.f, 0.f, 0.f, 0.f);
}

extern "C" void kernel_launch(void* const* d_in, const int* in_sizes, int n_in,
                              void* d_out, int out_size, void* d_ws, size_t ws_size,
                              hipStream_t stream)
{
    const float* x      = (const float*)d_in[0];
    const int*   esrc   = (const int*)d_in[1];
    const int*   edst   = (const int*)d_in[2];
    const float* lin_w  = (const float*)d_in[3];
    const float* lin_b  = (const float*)d_in[4];
    const float* attn_w = (const float*)d_in[5];
    const float* attn_b = (const float*)d_in[6];
    float* out = (float*)d_out;

    char* ws = (char*)d_ws;
    float*        hA    = (float*)(ws);                 // 25,600,000 B
    float*        h2    = (float*)(ws + 25600000);      // 25,600,000 B
    float*        e_buf = (float*)(ws + 51200000);      // 3,200,000 B
    float*        sl    = (float*)(ws + 54400000);      // 200,000 B
    float*        sr    = (float*)(ws + 54600000);      // 200,000 B
    unsigned int* m_u   = (unsigned int*)(ws + 54800000); // 200,000 B
    float*        denom = (float*)(ws + 55000000);      // 200,000 B

    // h2 must start at zero (ws is poisoned 0xAA before every call);
    // subsequent layers get it re-zeroed by relu_zero_kernel.
    hipMemsetAsync(h2, 0, (size_t)N_NODES * D * sizeof(float), stream);

    const float* cur = x;
    for (int l = 0; l < N_LAYERS; ++l) {
        hipMemsetAsync(m_u, 0, N_NODES * sizeof(unsigned int), stream);
        hipMemsetAsync(denom, 0, N_NODES * sizeof(float), stream);

        linear_kernel<<<(N_NODES + 31) / 32, 256, 0, stream>>>(
            cur, lin_w + (size_t)l * D * D, lin_b + (size_t)l * D, hA);
        attn_dot_kernel<<<(N_NODES * 64 + 255) / 256, 256, 0, stream>>>(
            hA, attn_w + (size_t)l * 2 * D, sl, sr);
        edge_max_kernel<<<(N_EDGES + 255) / 256, 256, 0, stream>>>(
            esrc, edst, sl, sr, attn_b + l, e_buf, m_u);
        edge_exp_kernel<<<(N_EDGES + 255) / 256, 256, 0, stream>>>(
            esrc, e_buf, m_u, denom);
        edge_scatter_kernel<<<(int)(((long long)N_EDGES * 64 + 255) / 256), 256, 0, stream>>>(
            esrc, edst, e_buf, denom, hA, h2);

        float* dest = (l == N_LAYERS - 1) ? out : hA;
        relu_zero_kernel<<<(N_NODES * D / 4 + 255) / 256, 256, 0, stream>>>(
            (float4*)h2, (float4*)dest);
        cur = hA;
    }
}

// Round 2
// 1015.567 us; speedup vs baseline: 1.9021x; 1.9021x over previous
//
#include <hip/hip_runtime.h>
#include <math.h>

#define N_NODES 50000
#define N_EDGES 800000
#define D 128
#define N_LAYERS 3

// ---------------------------------------------------------------------------
// Linear + bias + leaky_relu(0.2):  hout[r][c] = lrelu(sum_k hin[r][k]*W[k][c] + b[c])
// 32 rows per block, 256 threads: col = tid&127, row pair select = tid>>7.
// W staged in LDS in two 64-row K-chunks (32KB each).
// ---------------------------------------------------------------------------
__global__ __launch_bounds__(256) void linear_kernel(
    const float* __restrict__ hin, const float* __restrict__ W,
    const float* __restrict__ b, float* __restrict__ hout)
{
    __shared__ float Wl[64 * D];      // 32 KB
    __shared__ float rowsl[32 * 64];  // 8 KB

    int tid = threadIdx.x;
    int base = blockIdx.x * 32;
    int col = tid & 127;
    int rsel = tid >> 7;

    float acc[16];
#pragma unroll
    for (int i = 0; i < 16; ++i) acc[i] = 0.f;

    for (int kc = 0; kc < 2; ++kc) {
        __syncthreads();
        for (int j = tid * 4; j < 64 * D; j += 1024) {
            *(float4*)(Wl + j) = *(const float4*)(W + kc * 64 * D + j);
        }
        for (int j = tid; j < 32 * 64; j += 256) {
            int r = j >> 6, k = j & 63;
            int gr = base + r;
            rowsl[j] = (gr < N_NODES) ? hin[(size_t)gr * D + kc * 64 + k] : 0.f;
        }
        __syncthreads();
#pragma unroll
        for (int i = 0; i < 16; ++i) {
            const float* hr = rowsl + (2 * i + rsel) * 64;
            float a = acc[i];
#pragma unroll
            for (int k = 0; k < 64; ++k)
                a = fmaf(hr[k], Wl[k * D + col], a);
            acc[i] = a;
        }
    }

    float bc = b[col];
#pragma unroll
    for (int i = 0; i < 16; ++i) {
        int r = base + 2 * i + rsel;
        if (r < N_NODES) {
            float v = acc[i] + bc;
            v = v > 0.f ? v : 0.2f * v;
            hout[(size_t)r * D + col] = v;
        }
    }
}

// ---------------------------------------------------------------------------
// sr[n] = h[n] . aw_right[0:128]   (softmax weights only depend on sr: the
// per-source terms sl[i]+b are constant within a softmax row and cancel)
// One wave per node, butterfly reduce.
// ---------------------------------------------------------------------------
__global__ __launch_bounds__(256) void sr_kernel(
    const float* __restrict__ h, const float* __restrict__ awr,
    float* __restrict__ sr)
{
    int n = (blockIdx.x * 256 + threadIdx.x) >> 6;
    int lane = threadIdx.x & 63;
    if (n >= N_NODES) return;
    const float* hr = h + (size_t)n * D;
    float p = hr[lane] * awr[lane] + hr[lane + 64] * awr[lane + 64];
    for (int o = 32; o > 0; o >>= 1) p += __shfl_xor(p, o, 64);
    if (lane == 0) sr[n] = p;
}

// ---------------------------------------------------------------------------
// CSR build: histogram by src, single-block scan, fill csr_dst.
// ---------------------------------------------------------------------------
__global__ __launch_bounds__(256) void hist_kernel(
    const int* __restrict__ src, int* __restrict__ counts)
{
    int j = blockIdx.x * 256 + threadIdx.x;
    if (j >= N_EDGES) return;
    atomicAdd(counts + src[j], 1);
}

// counts arrives in `cursor`; exclusive-scan it into offsets[] and back into
// cursor[] (as the running fill pointer). Single block of 1024 threads.
__global__ __launch_bounds__(1024) void scan_kernel(
    int* __restrict__ cursor, int* __restrict__ offsets)
{
    __shared__ int buf[1024];
    __shared__ int carry_s;
    int tid = threadIdx.x;
    if (tid == 0) carry_s = 0;
    __syncthreads();
    for (int base = 0; base < N_NODES; base += 1024) {
        int i = base + tid;
        int v = (i < N_NODES) ? cursor[i] : 0;
        buf[tid] = v;
        __syncthreads();
        int x = v;
        for (int off = 1; off < 1024; off <<= 1) {
            int y = (tid >= off) ? buf[tid - off] : 0;
            __syncthreads();
            x += y;
            buf[tid] = x;
            __syncthreads();
        }
        int excl = carry_s + x - v;
        if (i < N_NODES) { offsets[i] = excl; cursor[i] = excl; }
        __syncthreads();
        if (tid == 1023) carry_s += x;
        __syncthreads();
    }
    if (tid == 0) offsets[N_NODES] = carry_s;
}

__global__ __launch_bounds__(256) void fill_kernel(
    const int* __restrict__ src, const int* __restrict__ dst,
    int* __restrict__ cursor, int* __restrict__ csr_dst)
{
    int j = blockIdx.x * 256 + threadIdx.x;
    if (j >= N_EDGES) return;
    int pos = atomicAdd(cursor + src[j], 1);
    csr_dst[pos] = dst[j];
}

// ---------------------------------------------------------------------------
// Fused softmax + gather, one wave per node:
//   alpha_k = exp(sr[d_k] - max)/sum;  out[n] = relu(sum_k alpha_k * h[d_k])
// No atomics. alphas staged in LDS for deg<=256 (true for this graph:
// Poisson(16) degrees; >256 handled by a recompute fallback).
// ---------------------------------------------------------------------------
__global__ __launch_bounds__(256) void gather_kernel(
    const int* __restrict__ offsets, const int* __restrict__ csr_dst,
    const float* __restrict__ sr, const float* __restrict__ h,
    float* __restrict__ out)
{
    __shared__ float alds[4][256];
    int wid = threadIdx.x >> 6, lane = threadIdx.x & 63;
    int n = blockIdx.x * 4 + wid;
    if (n >= N_NODES) return;
    int off = offsets[n];
    int deg = offsets[n + 1] - off;
    float* arow = alds[wid];

    int kcap = deg < 256 ? deg : 256;
    float ev[4];
    int dloc[4];
    float m = -INFINITY;
#pragma unroll
    for (int t = 0; t < 4; ++t) {
        int k = lane + t * 64;
        if (k < kcap) {
            int d = csr_dst[off + k];
            dloc[t] = d;
            float e = sr[d];
            ev[t] = e;
            m = fmaxf(m, e);
        }
    }
    for (int k = 256 + lane; k < deg; k += 64)
        m = fmaxf(m, sr[csr_dst[off + k]]);
    for (int o = 32; o > 0; o >>= 1) m = fmaxf(m, __shfl_xor(m, o, 64));

    float s = 0.f;
#pragma unroll
    for (int t = 0; t < 4; ++t) {
        int k = lane + t * 64;
        if (k < kcap) {
            float a = __expf(ev[t] - m);
            s += a;
            arow[k] = a;
        }
    }
    for (int k = 256 + lane; k < deg; k += 64)
        s += __expf(sr[csr_dst[off + k]] - m);
    for (int o = 32; o > 0; o >>= 1) s += __shfl_xor(s, o, 64);
    float inv = (deg > 0) ? 1.f / s : 0.f;

    float acc0 = 0.f, acc1 = 0.f;
    for (int k = 0; k < deg; ++k) {
        int t = k >> 6, sl = k & 63;
        int d;
        float a;
        if (k < 256) {
            switch (t) {
                case 0: d = __shfl(dloc[0], sl, 64); break;
                case 1: d = __shfl(dloc[1], sl, 64); break;
                case 2: d = __shfl(dloc[2], sl, 64); break;
                default: d = __shfl(dloc[3], sl, 64); break;
            }
            a = arow[k];
        } else {
            d = csr_dst[off + k];
            a = __expf(sr[d] - m);
        }
        const float* hr = h + (size_t)d * D;
        acc0 = fmaf(hr[lane], a, acc0);
        acc1 = fmaf(hr[lane + 64], a, acc1);
    }
    size_t o0 = (size_t)n * D + lane;
    out[o0] = fmaxf(acc0 * inv, 0.f);
    out[o0 + 64] = fmaxf(acc1 * inv, 0.f);
}

extern "C" void kernel_launch(void* const* d_in, const int* in_sizes, int n_in,
                              void* d_out, int out_size, void* d_ws, size_t ws_size,
                              hipStream_t stream)
{
    const float* x      = (const float*)d_in[0];
    const int*   esrc   = (const int*)d_in[1];
    const int*   edst   = (const int*)d_in[2];
    const float* lin_w  = (const float*)d_in[3];
    const float* lin_b  = (const float*)d_in[4];
    const float* attn_w = (const float*)d_in[5];
    float* out = (float*)d_out;

    char* ws = (char*)d_ws;
    float* hA      = (float*)(ws);                    // 25,600,000 B
    float* hB      = (float*)(ws + 25600000);         // 25,600,000 B
    float* sr      = (float*)(ws + 51200000);         // 200,000 B
    int*   offsets = (int*)(ws + 51400000);           // 200,004 B
    int*   cursor  = (int*)(ws + 51600008);           // 200,004 B
    int*   csr_dst = (int*)(ws + 51800016);           // 3,200,000 B

    // ---- CSR build (edge list is constant across layers) ----
    hipMemsetAsync(cursor, 0, N_NODES * sizeof(int), stream);
    hist_kernel<<<(N_EDGES + 255) / 256, 256, 0, stream>>>(esrc, cursor);
    scan_kernel<<<1, 1024, 0, stream>>>(cursor, offsets);
    fill_kernel<<<(N_EDGES + 255) / 256, 256, 0, stream>>>(esrc, edst, cursor, csr_dst);

    const float* cur = x;
    for (int l = 0; l < N_LAYERS; ++l) {
        linear_kernel<<<(N_NODES + 31) / 32, 256, 0, stream>>>(
            cur, lin_w + (size_t)l * D * D, lin_b + (size_t)l * D, hA);
        sr_kernel<<<(N_NODES * 64 + 255) / 256, 256, 0, stream>>>(
            hA, attn_w + (size_t)l * 2 * D + D, sr);
        float* dest = (l == N_LAYERS - 1) ? out : hB;
        gather_kernel<<<(N_NODES + 3) / 4, 256, 0, stream>>>(
            offsets, csr_dst, sr, hA, dest);
        cur = hB;
    }
}

// Round 3
// 527.124 us; speedup vs baseline: 3.6647x; 1.9266x over previous
//
#include <hip/hip_runtime.h>
#include <math.h>

#define N_NODES 50000
#define N_EDGES 800000
#define D 128
#define N_LAYERS 3

typedef _Float16 half8 __attribute__((ext_vector_type(8)));
typedef _Float16 half4 __attribute__((ext_vector_type(4)));
typedef _Float16 half2v __attribute__((ext_vector_type(2)));
typedef float f32x4 __attribute__((ext_vector_type(4)));

// ---------------------------------------------------------------------------
// One-time: Wt16[l][n][k] = (f16) W[l][k][n]  (transposed, f16)
// ---------------------------------------------------------------------------
__global__ __launch_bounds__(256) void prep_w_kernel(
    const float* __restrict__ W, _Float16* __restrict__ Wt)
{
    int idx = blockIdx.x * 256 + threadIdx.x;
    if (idx >= N_LAYERS * D * D) return;
    int l = idx >> 14, rem = idx & (D * D - 1);
    int k = rem >> 7, n = rem & 127;
    Wt[l * D * D + n * D + k] = (_Float16)W[idx];
}

// x (f32) -> x16 (f16)
__global__ __launch_bounds__(256) void convert_kernel(
    const float4* __restrict__ x, half4* __restrict__ x16, int n4)
{
    int i = blockIdx.x * 256 + threadIdx.x;
    if (i >= n4) return;
    float4 v = x[i];
    half4 o;
    o[0] = (_Float16)v.x; o[1] = (_Float16)v.y;
    o[2] = (_Float16)v.z; o[3] = (_Float16)v.w;
    x16[i] = o;
}

// ---------------------------------------------------------------------------
// MFMA linear: hout = leaky_relu(A @ W + b), A f16 [N,128], Wt f16 [n][k].
// Block = 4 waves x 16 rows = 64 rows. Full W^T staged in LDS (stride 130).
// Per wave: 8 n-tiles x 4 k-steps of v_mfma_f32_16x16x32_f16.
// A-frag: lane holds A[rowbase + (lane&15)][kstep*32 + (lane>>4)*8 ..+8].
// C/D: col = lane&15, row = (lane>>4)*4 + reg.
// ---------------------------------------------------------------------------
__global__ __launch_bounds__(256) void linear_mfma_kernel(
    const _Float16* __restrict__ A, const _Float16* __restrict__ Wt,
    const float* __restrict__ b, _Float16* __restrict__ hout)
{
    __shared__ _Float16 Wl[D * 130];
    int tid = threadIdx.x;
    for (int j = tid * 8; j < D * D; j += 2048) {
        int n = j >> 7, k = j & 127;
        *(half8*)(&Wl[n * 130 + k]) = *(const half8*)(Wt + j);
    }
    __syncthreads();

    int wid = tid >> 6, lane = tid & 63;
    int m = lane & 15, q = lane >> 4;
    int rowbase = blockIdx.x * 64 + wid * 16;
    int row = rowbase + m;

    half8 a[4];
    if (row < N_NODES) {
        const _Float16* ar = A + (size_t)row * D;
#pragma unroll
        for (int s = 0; s < 4; ++s)
            a[s] = *(const half8*)(ar + s * 32 + q * 8);
    } else {
#pragma unroll
        for (int s = 0; s < 4; ++s)
#pragma unroll
            for (int j = 0; j < 8; ++j) a[s][j] = (_Float16)0.f;
    }

    f32x4 acc[8];
#pragma unroll
    for (int t = 0; t < 8; ++t) acc[t] = (f32x4)(0.f);

#pragma unroll
    for (int s = 0; s < 4; ++s) {
#pragma unroll
        for (int t = 0; t < 8; ++t) {
            half8 bf = *(const half8*)(&Wl[(t * 16 + m) * 130 + s * 32 + q * 8]);
            acc[t] = __builtin_amdgcn_mfma_f32_16x16x32_f16(a[s], bf, acc[t], 0, 0, 0);
        }
    }

#pragma unroll
    for (int t = 0; t < 8; ++t) {
        int col = t * 16 + m;
        float bc = b[col];
#pragma unroll
        for (int r = 0; r < 4; ++r) {
            int orow = rowbase + q * 4 + r;
            if (orow < N_NODES) {
                float v = acc[t][r] + bc;
                v = v > 0.f ? v : 0.2f * v;
                hout[(size_t)orow * D + col] = (_Float16)v;
            }
        }
    }
}

// ---------------------------------------------------------------------------
// sr[n] = h16[n] . awr  (softmax weight; per-src terms cancel in softmax)
// ---------------------------------------------------------------------------
__global__ __launch_bounds__(256) void sr_kernel(
    const _Float16* __restrict__ h, const float* __restrict__ awr,
    float* __restrict__ sr)
{
    int n = (blockIdx.x * 256 + threadIdx.x) >> 6;
    int lane = threadIdx.x & 63;
    if (n >= N_NODES) return;
    half2v hv = *(const half2v*)(h + (size_t)n * D + 2 * lane);
    float p = (float)hv[0] * awr[2 * lane] + (float)hv[1] * awr[2 * lane + 1];
    for (int o = 32; o > 0; o >>= 1) p += __shfl_xor(p, o, 64);
    if (lane == 0) sr[n] = p;
}

// ---------------------------------------------------------------------------
// CSR build
// ---------------------------------------------------------------------------
__global__ __launch_bounds__(256) void hist_kernel(
    const int* __restrict__ src, int* __restrict__ counts)
{
    int j = blockIdx.x * 256 + threadIdx.x;
    if (j >= N_EDGES) return;
    atomicAdd(counts + src[j], 1);
}

__global__ __launch_bounds__(1024) void scan_kernel(
    int* __restrict__ cursor, int* __restrict__ offsets)
{
    __shared__ int buf[1024];
    __shared__ int carry_s;
    int tid = threadIdx.x;
    if (tid == 0) carry_s = 0;
    __syncthreads();
    for (int base = 0; base < N_NODES; base += 1024) {
        int i = base + tid;
        int v = (i < N_NODES) ? cursor[i] : 0;
        buf[tid] = v;
        __syncthreads();
        int x = v;
        for (int off = 1; off < 1024; off <<= 1) {
            int y = (tid >= off) ? buf[tid - off] : 0;
            __syncthreads();
            x += y;
            buf[tid] = x;
            __syncthreads();
        }
        int excl = carry_s + x - v;
        if (i < N_NODES) { offsets[i] = excl; cursor[i] = excl; }
        __syncthreads();
        if (tid == 1023) carry_s += x;
        __syncthreads();
    }
    if (tid == 0) offsets[N_NODES] = carry_s;
}

__global__ __launch_bounds__(256) void fill_kernel(
    const int* __restrict__ src, const int* __restrict__ dst,
    int* __restrict__ cursor, int* __restrict__ csr_dst)
{
    int j = blockIdx.x * 256 + threadIdx.x;
    if (j >= N_EDGES) return;
    int pos = atomicAdd(cursor + src[j], 1);
    csr_dst[pos] = dst[j];
}

// ---------------------------------------------------------------------------
// Fused softmax + gather, one wave per node, h in f16.
// Writes f16 (inner layers) or f32 (final layer).
// ---------------------------------------------------------------------------
__global__ __launch_bounds__(256) void gather_kernel(
    const int* __restrict__ offsets, const int* __restrict__ csr_dst,
    const float* __restrict__ sr, const _Float16* __restrict__ h,
    _Float16* __restrict__ out16, float* __restrict__ out32)
{
    __shared__ float alds[4][256];
    int wid = threadIdx.x >> 6, lane = threadIdx.x & 63;
    int n = blockIdx.x * 4 + wid;
    if (n >= N_NODES) return;
    int off = offsets[n];
    int deg = offsets[n + 1] - off;
    float* arow = alds[wid];

    int kcap = deg < 256 ? deg : 256;
    float ev[4];
    int dloc[4];
    float m = -INFINITY;
#pragma unroll
    for (int t = 0; t < 4; ++t) {
        int k = lane + t * 64;
        if (k < kcap) {
            int d = csr_dst[off + k];
            dloc[t] = d;
            float e = sr[d];
            ev[t] = e;
            m = fmaxf(m, e);
        }
    }
    for (int k = 256 + lane; k < deg; k += 64)
        m = fmaxf(m, sr[csr_dst[off + k]]);
    for (int o = 32; o > 0; o >>= 1) m = fmaxf(m, __shfl_xor(m, o, 64));

    float s = 0.f;
#pragma unroll
    for (int t = 0; t < 4; ++t) {
        int k = lane + t * 64;
        if (k < kcap) {
            float a = __expf(ev[t] - m);
            s += a;
            arow[k] = a;
        }
    }
    for (int k = 256 + lane; k < deg; k += 64)
        s += __expf(sr[csr_dst[off + k]] - m);
    for (int o = 32; o > 0; o >>= 1) s += __shfl_xor(s, o, 64);
    float inv = (deg > 0) ? 1.f / s : 0.f;

    float acc0 = 0.f, acc1 = 0.f;
    for (int k = 0; k < deg; ++k) {
        int t = k >> 6, sl = k & 63;
        int d;
        float a;
        if (k < 256) {
            switch (t) {
                case 0: d = __shfl(dloc[0], sl, 64); break;
                case 1: d = __shfl(dloc[1], sl, 64); break;
                case 2: d = __shfl(dloc[2], sl, 64); break;
                default: d = __shfl(dloc[3], sl, 64); break;
            }
            a = arow[k];
        } else {
            d = csr_dst[off + k];
            a = __expf(sr[d] - m);
        }
        half2v hv = *(const half2v*)(h + (size_t)d * D + 2 * lane);
        acc0 = fmaf((float)hv[0], a, acc0);
        acc1 = fmaf((float)hv[1], a, acc1);
    }
    float r0 = fmaxf(acc0 * inv, 0.f);
    float r1 = fmaxf(acc1 * inv, 0.f);
    if (out16) {
        half2v o;
        o[0] = (_Float16)r0;
        o[1] = (_Float16)r1;
        *(half2v*)(out16 + (size_t)n * D + 2 * lane) = o;
    } else {
        float2 o = make_float2(r0, r1);
        *(float2*)(out32 + (size_t)n * D + 2 * lane) = o;
    }
}

extern "C" void kernel_launch(void* const* d_in, const int* in_sizes, int n_in,
                              void* d_out, int out_size, void* d_ws, size_t ws_size,
                              hipStream_t stream)
{
    const float* x      = (const float*)d_in[0];
    const int*   esrc   = (const int*)d_in[1];
    const int*   edst   = (const int*)d_in[2];
    const float* lin_w  = (const float*)d_in[3];
    const float* lin_b  = (const float*)d_in[4];
    const float* attn_w = (const float*)d_in[5];
    float* out = (float*)d_out;

    char* ws = (char*)d_ws;
    _Float16* h16A    = (_Float16*)(ws);                 // 12,800,000 B
    _Float16* h16B    = (_Float16*)(ws + 12800000);      // 12,800,000 B
    float*    sr      = (float*)(ws + 25600000);         // 200,000 B
    int*      offsets = (int*)(ws + 25800000);           // 200,004 B
    int*      cursor  = (int*)(ws + 26000008);           // 200,004 B
    int*      csr_dst = (int*)(ws + 26200016);           // 3,200,000 B
    _Float16* Wt16    = (_Float16*)(ws + 29400016);      // 98,304 B

    // One-time prep: f16 transposed weights, f16 input, CSR by src.
    prep_w_kernel<<<(N_LAYERS * D * D + 255) / 256, 256, 0, stream>>>(lin_w, Wt16);
    convert_kernel<<<(N_NODES * D / 4 + 255) / 256, 256, 0, stream>>>(
        (const float4*)x, (half4*)h16B, N_NODES * D / 4);
    hipMemsetAsync(cursor, 0, N_NODES * sizeof(int), stream);
    hist_kernel<<<(N_EDGES + 255) / 256, 256, 0, stream>>>(esrc, cursor);
    scan_kernel<<<1, 1024, 0, stream>>>(cursor, offsets);
    fill_kernel<<<(N_EDGES + 255) / 256, 256, 0, stream>>>(esrc, edst, cursor, csr_dst);

    for (int l = 0; l < N_LAYERS; ++l) {
        linear_mfma_kernel<<<(N_NODES + 63) / 64, 256, 0, stream>>>(
            h16B, Wt16 + (size_t)l * D * D, lin_b + (size_t)l * D, h16A);
        sr_kernel<<<(N_NODES * 64 + 255) / 256, 256, 0, stream>>>(
            h16A, attn_w + (size_t)l * 2 * D + D, sr);
        bool last = (l == N_LAYERS - 1);
        gather_kernel<<<(N_NODES + 3) / 4, 256, 0, stream>>>(
            offsets, csr_dst, sr, h16A,
            last ? (_Float16*)nullptr : h16B, last ? out : nullptr);
    }
}

// Round 4
// 418.018 us; speedup vs baseline: 4.6212x; 1.2610x over previous
//
#include <hip/hip_runtime.h>
#include <math.h>

#define N_NODES 50000
#define N_EDGES 800000
#define D 128
#define N_LAYERS 3
#define SCAN_NB ((N_NODES + 1023) / 1024)  // 49

typedef _Float16 half8 __attribute__((ext_vector_type(8)));
typedef _Float16 half4 __attribute__((ext_vector_type(4)));
typedef _Float16 half2v __attribute__((ext_vector_type(2)));
typedef float f32x4 __attribute__((ext_vector_type(4)));

// ---------------------------------------------------------------------------
// One-time: Wt16[l][n][k] = (f16) W[l][k][n]  (transposed, f16)
// ---------------------------------------------------------------------------
__global__ __launch_bounds__(256) void prep_w_kernel(
    const float* __restrict__ W, _Float16* __restrict__ Wt)
{
    int idx = blockIdx.x * 256 + threadIdx.x;
    if (idx >= N_LAYERS * D * D) return;
    int l = idx >> 14, rem = idx & (D * D - 1);
    int k = rem >> 7, n = rem & 127;
    Wt[l * D * D + n * D + k] = (_Float16)W[idx];
}

// x (f32) -> x16 (f16)
__global__ __launch_bounds__(256) void convert_kernel(
    const float4* __restrict__ x, half4* __restrict__ x16, int n4)
{
    int i = blockIdx.x * 256 + threadIdx.x;
    if (i >= n4) return;
    float4 v = x[i];
    half4 o;
    o[0] = (_Float16)v.x; o[1] = (_Float16)v.y;
    o[2] = (_Float16)v.z; o[3] = (_Float16)v.w;
    x16[i] = o;
}

// ---------------------------------------------------------------------------
// MFMA linear + fused sr:  hout = leaky_relu(A @ W + b);  sr[n] = hout[n].awr
// Block = 4 waves x 16 rows = 64 rows. Full W^T staged in LDS (stride 130).
// A-frag: lane holds A[rowbase + (lane&15)][kstep*32 + (lane>>4)*8 ..+8].
// C/D: col = lane&15 (within 16-tile), row = (lane>>4)*4 + reg.
// sr reduction: for fixed (q,r) the 16 lanes m=0..15 of group q hold all 128
// cols (8 t-tiles each) -> partial dot + shfl_xor(1,2,4,8) within the group.
// ---------------------------------------------------------------------------
__global__ __launch_bounds__(256) void linear_mfma_kernel(
    const _Float16* __restrict__ A, const _Float16* __restrict__ Wt,
    const float* __restrict__ b, const float* __restrict__ awr,
    _Float16* __restrict__ hout, float* __restrict__ sr)
{
    __shared__ _Float16 Wl[D * 130];
    int tid = threadIdx.x;
    for (int j = tid * 8; j < D * D; j += 2048) {
        int n = j >> 7, k = j & 127;
        *(half8*)(&Wl[n * 130 + k]) = *(const half8*)(Wt + j);
    }
    __syncthreads();

    int wid = tid >> 6, lane = tid & 63;
    int m = lane & 15, q = lane >> 4;
    int rowbase = blockIdx.x * 64 + wid * 16;
    int row = rowbase + m;

    half8 a[4];
    if (row < N_NODES) {
        const _Float16* ar = A + (size_t)row * D;
#pragma unroll
        for (int s = 0; s < 4; ++s)
            a[s] = *(const half8*)(ar + s * 32 + q * 8);
    } else {
#pragma unroll
        for (int s = 0; s < 4; ++s)
#pragma unroll
            for (int j = 0; j < 8; ++j) a[s][j] = (_Float16)0.f;
    }

    f32x4 acc[8];
#pragma unroll
    for (int t = 0; t < 8; ++t) acc[t] = (f32x4)(0.f);

#pragma unroll
    for (int s = 0; s < 4; ++s) {
#pragma unroll
        for (int t = 0; t < 8; ++t) {
            half8 bf = *(const half8*)(&Wl[(t * 16 + m) * 130 + s * 32 + q * 8]);
            acc[t] = __builtin_amdgcn_mfma_f32_16x16x32_f16(a[s], bf, acc[t], 0, 0, 0);
        }
    }

    float sp[4] = {0.f, 0.f, 0.f, 0.f};
#pragma unroll
    for (int t = 0; t < 8; ++t) {
        int col = t * 16 + m;
        float bc = b[col];
        float ac = awr[col];
#pragma unroll
        for (int r = 0; r < 4; ++r) {
            int orow = rowbase + q * 4 + r;
            float v = acc[t][r] + bc;
            v = v > 0.f ? v : 0.2f * v;
            sp[r] = fmaf(v, ac, sp[r]);
            if (orow < N_NODES)
                hout[(size_t)orow * D + col] = (_Float16)v;
        }
    }
    // reduce sp[r] across the 16 lanes of this q-group
#pragma unroll
    for (int r = 0; r < 4; ++r) {
#pragma unroll
        for (int o = 1; o < 16; o <<= 1)
            sp[r] += __shfl_xor(sp[r], o, 64);
    }
    if (m == 0) {
#pragma unroll
        for (int r = 0; r < 4; ++r) {
            int orow = rowbase + q * 4 + r;
            if (orow < N_NODES) sr[orow] = sp[r];
        }
    }
}

// ---------------------------------------------------------------------------
// CSR build: histogram, hierarchical scan (block sums -> wave scan -> local)
// ---------------------------------------------------------------------------
__global__ __launch_bounds__(256) void hist_kernel(
    const int* __restrict__ src, int* __restrict__ counts)
{
    int j = blockIdx.x * 256 + threadIdx.x;
    if (j >= N_EDGES) return;
    atomicAdd(counts + src[j], 1);
}

// Stage 1: per-block (1024-element) degree sums
__global__ __launch_bounds__(256) void degsum_kernel(
    const int* __restrict__ counts, int* __restrict__ sums)
{
    __shared__ int wsum[4];
    int tid = threadIdx.x;
    int base = blockIdx.x * 1024 + tid * 4;
    int s = 0;
#pragma unroll
    for (int j = 0; j < 4; ++j) {
        int i = base + j;
        if (i < N_NODES) s += counts[i];
    }
    for (int o = 32; o > 0; o >>= 1) s += __shfl_xor(s, o, 64);
    int lane = tid & 63, wid = tid >> 6;
    if (lane == 0) wsum[wid] = s;
    __syncthreads();
    if (tid == 0) sums[blockIdx.x] = wsum[0] + wsum[1] + wsum[2] + wsum[3];
}

// Stage 2: single wave exclusive-scans the (<=64) block sums in place
__global__ __launch_bounds__(64) void scan_sums_kernel(
    int* __restrict__ sums, int* __restrict__ offsets)
{
    int lane = threadIdx.x;
    int orig = (lane < SCAN_NB) ? sums[lane] : 0;
    int v = orig;
    for (int o = 1; o < 64; o <<= 1) {
        int y = __shfl_up(v, o, 64);
        if (lane >= o) v += y;
    }
    if (lane < SCAN_NB) sums[lane] = v - orig;
    if (lane == 63) offsets[N_NODES] = v;  // grand total
}

// Stage 3: per-block local scan + base; writes offsets and cursor
__global__ __launch_bounds__(256) void local_scan_kernel(
    const int* __restrict__ counts, const int* __restrict__ sums_excl,
    int* __restrict__ offsets, int* __restrict__ cursor)
{
    __shared__ int wsum[4];
    int tid = threadIdx.x;
    int lane = tid & 63, wid = tid >> 6;
    int base = blockIdx.x * 1024 + tid * 4;
    int c[4];
    int tsum = 0;
#pragma unroll
    for (int j = 0; j < 4; ++j) {
        int i = base + j;
        c[j] = (i < N_NODES) ? counts[i] : 0;
        tsum += c[j];
    }
    int v = tsum;
    for (int o = 1; o < 64; o <<= 1) {
        int y = __shfl_up(v, o, 64);
        if (lane >= o) v += y;
    }
    if (lane == 63) wsum[wid] = v;
    __syncthreads();
    int wbase = 0;
    for (int w = 0; w < wid; ++w) wbase += wsum[w];
    int run = sums_excl[blockIdx.x] + wbase + (v - tsum);
#pragma unroll
    for (int j = 0; j < 4; ++j) {
        int i = base + j;
        if (i < N_NODES) { offsets[i] = run; cursor[i] = run; }
        run += c[j];
    }
}

__global__ __launch_bounds__(256) void fill_kernel(
    const int* __restrict__ src, const int* __restrict__ dst,
    int* __restrict__ cursor, int* __restrict__ csr_dst)
{
    int j = blockIdx.x * 256 + threadIdx.x;
    if (j >= N_EDGES) return;
    int pos = atomicAdd(cursor + src[j], 1);
    csr_dst[pos] = dst[j];
}

// ---------------------------------------------------------------------------
// Fused softmax + gather, one wave per node, h in f16.
// Writes f16 (inner layers) or f32 (final layer).
// ---------------------------------------------------------------------------
__global__ __launch_bounds__(256) void gather_kernel(
    const int* __restrict__ offsets, const int* __restrict__ csr_dst,
    const float* __restrict__ sr, const _Float16* __restrict__ h,
    _Float16* __restrict__ out16, float* __restrict__ out32)
{
    __shared__ float alds[4][256];
    int wid = threadIdx.x >> 6, lane = threadIdx.x & 63;
    int n = blockIdx.x * 4 + wid;
    if (n >= N_NODES) return;
    int off = offsets[n];
    int deg = offsets[n + 1] - off;
    float* arow = alds[wid];

    int kcap = deg < 256 ? deg : 256;
    float ev[4];
    int dloc[4];
    float m = -INFINITY;
#pragma unroll
    for (int t = 0; t < 4; ++t) {
        int k = lane + t * 64;
        if (k < kcap) {
            int d = csr_dst[off + k];
            dloc[t] = d;
            float e = sr[d];
            ev[t] = e;
            m = fmaxf(m, e);
        }
    }
    for (int k = 256 + lane; k < deg; k += 64)
        m = fmaxf(m, sr[csr_dst[off + k]]);
    for (int o = 32; o > 0; o >>= 1) m = fmaxf(m, __shfl_xor(m, o, 64));

    float s = 0.f;
#pragma unroll
    for (int t = 0; t < 4; ++t) {
        int k = lane + t * 64;
        if (k < kcap) {
            float a = __expf(ev[t] - m);
            s += a;
            arow[k] = a;
        }
    }
    for (int k = 256 + lane; k < deg; k += 64)
        s += __expf(sr[csr_dst[off + k]] - m);
    for (int o = 32; o > 0; o >>= 1) s += __shfl_xor(s, o, 64);
    float inv = (deg > 0) ? 1.f / s : 0.f;

    float acc0 = 0.f, acc1 = 0.f;
    for (int k = 0; k < deg; ++k) {
        int t = k >> 6, sl = k & 63;
        int d;
        float a;
        if (k < 256) {
            switch (t) {
                case 0: d = __shfl(dloc[0], sl, 64); break;
                case 1: d = __shfl(dloc[1], sl, 64); break;
                case 2: d = __shfl(dloc[2], sl, 64); break;
                default: d = __shfl(dloc[3], sl, 64); break;
            }
            a = arow[k];
        } else {
            d = csr_dst[off + k];
            a = __expf(sr[d] - m);
        }
        half2v hv = *(const half2v*)(h + (size_t)d * D + 2 * lane);
        acc0 = fmaf((float)hv[0], a, acc0);
        acc1 = fmaf((float)hv[1], a, acc1);
    }
    float r0 = fmaxf(acc0 * inv, 0.f);
    float r1 = fmaxf(acc1 * inv, 0.f);
    if (out16) {
        half2v o;
        o[0] = (_Float16)r0;
        o[1] = (_Float16)r1;
        *(half2v*)(out16 + (size_t)n * D + 2 * lane) = o;
    } else {
        float2 o = make_float2(r0, r1);
        *(float2*)(out32 + (size_t)n * D + 2 * lane) = o;
    }
}

extern "C" void kernel_launch(void* const* d_in, const int* in_sizes, int n_in,
                              void* d_out, int out_size, void* d_ws, size_t ws_size,
                              hipStream_t stream)
{
    const float* x      = (const float*)d_in[0];
    const int*   esrc   = (const int*)d_in[1];
    const int*   edst   = (const int*)d_in[2];
    const float* lin_w  = (const float*)d_in[3];
    const float* lin_b  = (const float*)d_in[4];
    const float* attn_w = (const float*)d_in[5];
    float* out = (float*)d_out;

    char* ws = (char*)d_ws;
    _Float16* h16A    = (_Float16*)(ws);                 // 12,800,000 B
    _Float16* h16B    = (_Float16*)(ws + 12800000);      // 12,800,000 B
    float*    sr      = (float*)(ws + 25600000);         // 200,000 B
    int*      offsets = (int*)(ws + 25800000);           // 200,004 B
    int*      cursor  = (int*)(ws + 26000008);           // 200,004 B
    int*      counts  = (int*)(ws + 26200016);           // 200,000 B
    int*      bsums   = (int*)(ws + 26400016);           // 256 B
    int*      csr_dst = (int*)(ws + 26400272);           // 3,200,000 B
    _Float16* Wt16    = (_Float16*)(ws + 29600272);      // 98,304 B

    // One-time prep: f16 transposed weights, f16 input, CSR by src.
    prep_w_kernel<<<(N_LAYERS * D * D + 255) / 256, 256, 0, stream>>>(lin_w, Wt16);
    convert_kernel<<<(N_NODES * D / 4 + 255) / 256, 256, 0, stream>>>(
        (const float4*)x, (half4*)h16B, N_NODES * D / 4);
    hipMemsetAsync(counts, 0, N_NODES * sizeof(int), stream);
    hist_kernel<<<(N_EDGES + 255) / 256, 256, 0, stream>>>(esrc, counts);
    degsum_kernel<<<SCAN_NB, 256, 0, stream>>>(counts, bsums);
    scan_sums_kernel<<<1, 64, 0, stream>>>(bsums, offsets);
    local_scan_kernel<<<SCAN_NB, 256, 0, stream>>>(counts, bsums, offsets, cursor);
    fill_kernel<<<(N_EDGES + 255) / 256, 256, 0, stream>>>(esrc, edst, cursor, csr_dst);

    for (int l = 0; l < N_LAYERS; ++l) {
        linear_mfma_kernel<<<(N_NODES + 63) / 64, 256, 0, stream>>>(
            h16B, Wt16 + (size_t)l * D * D, lin_b + (size_t)l * D,
            attn_w + (size_t)l * 2 * D + D, h16A, sr);
        bool last = (l == N_LAYERS - 1);
        gather_kernel<<<(N_NODES + 3) / 4, 256, 0, stream>>>(
            offsets, csr_dst, sr, h16A,
            last ? (_Float16*)nullptr : h16B, last ? out : nullptr);
    }
}

// Round 5
// 325.756 us; speedup vs baseline: 5.9300x; 1.2832x over previous
//
#include <hip/hip_runtime.h>
#include <math.h>

#define N_NODES 50000
#define N_EDGES 800000
#define D 128
#define N_LAYERS 3
#define SCAN_NB ((N_NODES + 1023) / 1024)  // 49

typedef _Float16 half8 __attribute__((ext_vector_type(8)));
typedef _Float16 half2v __attribute__((ext_vector_type(2)));
typedef float f32x4 __attribute__((ext_vector_type(4)));

// ---------------------------------------------------------------------------
// One-time: Wt16[l][n][k] = (f16) W[l][k][n]  (transposed, f16)
// ---------------------------------------------------------------------------
__global__ __launch_bounds__(256) void prep_w_kernel(
    const float* __restrict__ W, _Float16* __restrict__ Wt)
{
    int idx = blockIdx.x * 256 + threadIdx.x;
    if (idx >= N_LAYERS * D * D) return;
    int l = idx >> 14, rem = idx & (D * D - 1);
    int k = rem >> 7, n = rem & 127;
    Wt[l * D * D + n * D + k] = (_Float16)W[idx];
}

// ---------------------------------------------------------------------------
// MFMA linear + fused sr:  hout = leaky_relu(A @ W + b);  sr[n] = hout[n].awr
// Block = 4 waves x 16 rows = 64 rows. Full W^T staged in LDS (stride 130).
// A-frag: lane holds A[rowbase + (lane&15)][kstep*32 + (lane>>4)*8 ..+8].
// C/D: col = lane&15 (within 16-tile), row = (lane>>4)*4 + reg.
// F32IN: first layer reads f32 x directly (convert fused into A-load).
// ---------------------------------------------------------------------------
template <bool F32IN>
__global__ __launch_bounds__(256) void linear_mfma_kernel(
    const void* __restrict__ Ain, const _Float16* __restrict__ Wt,
    const float* __restrict__ b, const float* __restrict__ awr,
    _Float16* __restrict__ hout, float* __restrict__ sr)
{
    __shared__ _Float16 Wl[D * 130];
    int tid = threadIdx.x;
    for (int j = tid * 8; j < D * D; j += 2048) {
        int n = j >> 7, k = j & 127;
        *(half8*)(&Wl[n * 130 + k]) = *(const half8*)(Wt + j);
    }
    __syncthreads();

    int wid = tid >> 6, lane = tid & 63;
    int m = lane & 15, q = lane >> 4;
    int rowbase = blockIdx.x * 64 + wid * 16;
    int row = rowbase + m;

    half8 a[4];
    if (row < N_NODES) {
        if (F32IN) {
            const float* ar = (const float*)Ain + (size_t)row * D;
#pragma unroll
            for (int s = 0; s < 4; ++s) {
                float4 lo = *(const float4*)(ar + s * 32 + q * 8);
                float4 hi = *(const float4*)(ar + s * 32 + q * 8 + 4);
                a[s][0] = (_Float16)lo.x; a[s][1] = (_Float16)lo.y;
                a[s][2] = (_Float16)lo.z; a[s][3] = (_Float16)lo.w;
                a[s][4] = (_Float16)hi.x; a[s][5] = (_Float16)hi.y;
                a[s][6] = (_Float16)hi.z; a[s][7] = (_Float16)hi.w;
            }
        } else {
            const _Float16* ar = (const _Float16*)Ain + (size_t)row * D;
#pragma unroll
            for (int s = 0; s < 4; ++s)
                a[s] = *(const half8*)(ar + s * 32 + q * 8);
        }
    } else {
#pragma unroll
        for (int s = 0; s < 4; ++s)
#pragma unroll
            for (int j = 0; j < 8; ++j) a[s][j] = (_Float16)0.f;
    }

    f32x4 acc[8];
#pragma unroll
    for (int t = 0; t < 8; ++t) acc[t] = (f32x4)(0.f);

#pragma unroll
    for (int s = 0; s < 4; ++s) {
#pragma unroll
        for (int t = 0; t < 8; ++t) {
            half8 bf = *(const half8*)(&Wl[(t * 16 + m) * 130 + s * 32 + q * 8]);
            acc[t] = __builtin_amdgcn_mfma_f32_16x16x32_f16(a[s], bf, acc[t], 0, 0, 0);
        }
    }

    float sp[4] = {0.f, 0.f, 0.f, 0.f};
#pragma unroll
    for (int t = 0; t < 8; ++t) {
        int col = t * 16 + m;
        float bc = b[col];
        float ac = awr[col];
#pragma unroll
        for (int r = 0; r < 4; ++r) {
            int orow = rowbase + q * 4 + r;
            float v = acc[t][r] + bc;
            v = v > 0.f ? v : 0.2f * v;
            sp[r] = fmaf(v, ac, sp[r]);
            if (orow < N_NODES)
                hout[(size_t)orow * D + col] = (_Float16)v;
        }
    }
#pragma unroll
    for (int r = 0; r < 4; ++r) {
#pragma unroll
        for (int o = 1; o < 16; o <<= 1)
            sp[r] += __shfl_xor(sp[r], o, 64);
    }
    if (m == 0) {
#pragma unroll
        for (int r = 0; r < 4; ++r) {
            int orow = rowbase + q * 4 + r;
            if (orow < N_NODES) sr[orow] = sp[r];
        }
    }
}

// ---------------------------------------------------------------------------
// CSR build: histogram, hierarchical scan, fill
// ---------------------------------------------------------------------------
__global__ __launch_bounds__(256) void hist_kernel(
    const int* __restrict__ src, int* __restrict__ counts)
{
    int j = blockIdx.x * 256 + threadIdx.x;
    if (j >= N_EDGES) return;
    atomicAdd(counts + src[j], 1);
}

__global__ __launch_bounds__(256) void degsum_kernel(
    const int* __restrict__ counts, int* __restrict__ sums)
{
    __shared__ int wsum[4];
    int tid = threadIdx.x;
    int base = blockIdx.x * 1024 + tid * 4;
    int s = 0;
#pragma unroll
    for (int j = 0; j < 4; ++j) {
        int i = base + j;
        if (i < N_NODES) s += counts[i];
    }
    for (int o = 32; o > 0; o >>= 1) s += __shfl_xor(s, o, 64);
    int lane = tid & 63, wid = tid >> 6;
    if (lane == 0) wsum[wid] = s;
    __syncthreads();
    if (tid == 0) sums[blockIdx.x] = wsum[0] + wsum[1] + wsum[2] + wsum[3];
}

__global__ __launch_bounds__(64) void scan_sums_kernel(
    int* __restrict__ sums, int* __restrict__ offsets)
{
    int lane = threadIdx.x;
    int orig = (lane < SCAN_NB) ? sums[lane] : 0;
    int v = orig;
    for (int o = 1; o < 64; o <<= 1) {
        int y = __shfl_up(v, o, 64);
        if (lane >= o) v += y;
    }
    if (lane < SCAN_NB) sums[lane] = v - orig;
    if (lane == 63) offsets[N_NODES] = v;
}

__global__ __launch_bounds__(256) void local_scan_kernel(
    const int* __restrict__ counts, const int* __restrict__ sums_excl,
    int* __restrict__ offsets, int* __restrict__ cursor)
{
    __shared__ int wsum[4];
    int tid = threadIdx.x;
    int lane = tid & 63, wid = tid >> 6;
    int base = blockIdx.x * 1024 + tid * 4;
    int c[4];
    int tsum = 0;
#pragma unroll
    for (int j = 0; j < 4; ++j) {
        int i = base + j;
        c[j] = (i < N_NODES) ? counts[i] : 0;
        tsum += c[j];
    }
    int v = tsum;
    for (int o = 1; o < 64; o <<= 1) {
        int y = __shfl_up(v, o, 64);
        if (lane >= o) v += y;
    }
    if (lane == 63) wsum[wid] = v;
    __syncthreads();
    int wbase = 0;
    for (int w = 0; w < wid; ++w) wbase += wsum[w];
    int run = sums_excl[blockIdx.x] + wbase + (v - tsum);
#pragma unroll
    for (int j = 0; j < 4; ++j) {
        int i = base + j;
        if (i < N_NODES) { offsets[i] = run; cursor[i] = run; }
        run += c[j];
    }
}

__global__ __launch_bounds__(256) void fill_kernel(
    const int* __restrict__ src, const int* __restrict__ dst,
    int* __restrict__ cursor, int* __restrict__ csr_dst)
{
    int j = blockIdx.x * 256 + threadIdx.x;
    if (j >= N_EDGES) return;
    int pos = atomicAdd(cursor + src[j], 1);
    csr_dst[pos] = dst[j];
}

// ---------------------------------------------------------------------------
// Fused softmax + gather, one wave per node, h in f16.
// idx + unnormalized alphas staged in LDS (per-wave rows), accumulate loop
// unrolled x4 with 4 independent row loads in flight.
// ---------------------------------------------------------------------------
__global__ __launch_bounds__(256) void gather_kernel(
    const int* __restrict__ offsets, const int* __restrict__ csr_dst,
    const float* __restrict__ sr, const _Float16* __restrict__ h,
    _Float16* __restrict__ out16, float* __restrict__ out32)
{
    __shared__ int   ilds[4][260];  // 260: rows stay 16B-aligned
    __shared__ float alds[4][260];
    int wid = threadIdx.x >> 6, lane = threadIdx.x & 63;
    int n = blockIdx.x * 4 + wid;
    if (n >= N_NODES) return;
    int off = offsets[n];
    int deg = offsets[n + 1] - off;
    int* irow = ilds[wid];
    float* arow = alds[wid];

    int kcap = deg < 256 ? deg : 256;
    float ev[4];
    float m = -INFINITY;
#pragma unroll
    for (int t = 0; t < 4; ++t) {
        int k = t * 64 + lane;
        if (k < kcap) {
            int d = csr_dst[off + k];
            irow[k] = d;
            float e = sr[d];
            ev[t] = e;
            m = fmaxf(m, e);
        }
    }
    for (int k = 256 + lane; k < deg; k += 64)
        m = fmaxf(m, sr[csr_dst[off + k]]);
    for (int o = 32; o > 0; o >>= 1) m = fmaxf(m, __shfl_xor(m, o, 64));

    float s = 0.f;
#pragma unroll
    for (int t = 0; t < 4; ++t) {
        int k = t * 64 + lane;
        if (k < kcap) {
            float a = __expf(ev[t] - m);
            arow[k] = a;
            s += a;
        }
    }
    for (int k = 256 + lane; k < deg; k += 64)
        s += __expf(sr[csr_dst[off + k]] - m);
    for (int o = 32; o > 0; o >>= 1) s += __shfl_xor(s, o, 64);
    float inv = (deg > 0) ? 1.f / s : 0.f;

    // accumulate: unroll x4, 4 independent scattered row loads in flight
    float acc0 = 0.f, acc1 = 0.f;
    const _Float16* hl = h + 2 * lane;
    int k = 0;
    int kcap4 = kcap & ~3;
    for (; k < kcap4; k += 4) {
        int4 di = *(const int4*)(irow + k);      // broadcast LDS reads
        float4 ai = *(const float4*)(arow + k);
        half2v h0 = *(const half2v*)(hl + (size_t)di.x * D);
        half2v h1 = *(const half2v*)(hl + (size_t)di.y * D);
        half2v h2 = *(const half2v*)(hl + (size_t)di.z * D);
        half2v h3 = *(const half2v*)(hl + (size_t)di.w * D);
        acc0 = fmaf((float)h0[0], ai.x, acc0);
        acc1 = fmaf((float)h0[1], ai.x, acc1);
        acc0 = fmaf((float)h1[0], ai.y, acc0);
        acc1 = fmaf((float)h1[1], ai.y, acc1);
        acc0 = fmaf((float)h2[0], ai.z, acc0);
        acc1 = fmaf((float)h2[1], ai.z, acc1);
        acc0 = fmaf((float)h3[0], ai.w, acc0);
        acc1 = fmaf((float)h3[1], ai.w, acc1);
    }
    for (; k < kcap; ++k) {
        int d = irow[k];
        float a = arow[k];
        half2v hv = *(const half2v*)(hl + (size_t)d * D);
        acc0 = fmaf((float)hv[0], a, acc0);
        acc1 = fmaf((float)hv[1], a, acc1);
    }
    for (k = 256; k < deg; ++k) {  // ultra-rare deep tail
        int d = csr_dst[off + k];
        float a = __expf(sr[d] - m);
        half2v hv = *(const half2v*)(hl + (size_t)d * D);
        acc0 = fmaf((float)hv[0], a, acc0);
        acc1 = fmaf((float)hv[1], a, acc1);
    }

    float r0 = fmaxf(acc0 * inv, 0.f);
    float r1 = fmaxf(acc1 * inv, 0.f);
    if (out16) {
        half2v o;
        o[0] = (_Float16)r0;
        o[1] = (_Float16)r1;
        *(half2v*)(out16 + (size_t)n * D + 2 * lane) = o;
    } else {
        float2 o = make_float2(r0, r1);
        *(float2*)(out32 + (size_t)n * D + 2 * lane) = o;
    }
}

extern "C" void kernel_launch(void* const* d_in, const int* in_sizes, int n_in,
                              void* d_out, int out_size, void* d_ws, size_t ws_size,
                              hipStream_t stream)
{
    const float* x      = (const float*)d_in[0];
    const int*   esrc   = (const int*)d_in[1];
    const int*   edst   = (const int*)d_in[2];
    const float* lin_w  = (const float*)d_in[3];
    const float* lin_b  = (const float*)d_in[4];
    const float* attn_w = (const float*)d_in[5];
    float* out = (float*)d_out;

    char* ws = (char*)d_ws;
    _Float16* h16A    = (_Float16*)(ws);                 // 12,800,000 B
    _Float16* h16B    = (_Float16*)(ws + 12800000);      // 12,800,000 B
    float*    sr      = (float*)(ws + 25600000);         // 200,000 B
    int*      offsets = (int*)(ws + 25800000);           // 200,004 B
    int*      cursor  = (int*)(ws + 26000008);           // 200,004 B
    int*      counts  = (int*)(ws + 26200016);           // 200,000 B
    int*      bsums   = (int*)(ws + 26400016);           // 256 B
    int*      csr_dst = (int*)(ws + 26400272);           // 3,200,000 B
    _Float16* Wt16    = (_Float16*)(ws + 29600272);      // 98,304 B

    // One-time prep: f16 transposed weights, CSR by src.
    prep_w_kernel<<<(N_LAYERS * D * D + 255) / 256, 256, 0, stream>>>(lin_w, Wt16);
    hipMemsetAsync(counts, 0, N_NODES * sizeof(int), stream);
    hist_kernel<<<(N_EDGES + 255) / 256, 256, 0, stream>>>(esrc, counts);
    degsum_kernel<<<SCAN_NB, 256, 0, stream>>>(counts, bsums);
    scan_sums_kernel<<<1, 64, 0, stream>>>(bsums, offsets);
    local_scan_kernel<<<SCAN_NB, 256, 0, stream>>>(counts, bsums, offsets, cursor);
    fill_kernel<<<(N_EDGES + 255) / 256, 256, 0, stream>>>(esrc, edst, cursor, csr_dst);

    for (int l = 0; l < N_LAYERS; ++l) {
        const void* A = (l == 0) ? (const void*)x : (const void*)h16B;
        if (l == 0)
            linear_mfma_kernel<true><<<(N_NODES + 63) / 64, 256, 0, stream>>>(
                A, Wt16 + (size_t)l * D * D, lin_b + (size_t)l * D,
                attn_w + (size_t)l * 2 * D + D, h16A, sr);
        else
            linear_mfma_kernel<false><<<(N_NODES + 63) / 64, 256, 0, stream>>>(
                A, Wt16 + (size_t)l * D * D, lin_b + (size_t)l * D,
                attn_w + (size_t)l * 2 * D + D, h16A, sr);
        bool last = (l == N_LAYERS - 1);
        gather_kernel<<<(N_NODES + 3) / 4, 256, 0, stream>>>(
            offsets, csr_dst, sr, h16A,
            last ? (_Float16*)nullptr : h16B, last ? out : nullptr);
    }
}